// Round 8
// baseline (178.047 us; speedup 1.0000x reference)
//
#include <hip/hip_runtime.h>
#include <math.h>

// Problem constants (from reference)
constexpr int IC   = 8;    // in channels
constexpr int OC   = 32;   // out channels
constexpr int KS   = 5;    // kernel size
constexpr int B_   = 16;   // batch
constexpr int HW_  = 128;  // H = W
constexpr int FH   = 124;  // output spatial (H - KS + 1)
constexpr int KTAP = KS * KS; // 25
constexpr int OG   = 4;    // output-channel groups (blockIdx.z)
constexpr int OPG  = 8;    // output channels per group
constexpr int RPB  = 4;    // output rows per block (1 per wave)
constexpr int XR   = RPB + KS - 1;  // 8 x-rows per LDS tile
constexpr int DW   = HW_ / 2;       // 64 packed dwords per row

typedef _Float16 h2 __attribute__((ext_vector_type(2)));

__device__ __forceinline__ h2 bc2(unsigned u) { return __builtin_bit_cast(h2, u); }
__device__ __forceinline__ unsigned pkf(float a, float b) {
    return __builtin_bit_cast(unsigned, __builtin_amdgcn_cvt_pkrtz(a, b));
}

// ---------------------------------------------------------------------------
// Pack -K_hit / -K_miss into f16x2 broadcast pairs.
// Layout: Kpk[((c*OG+g)*KTAP + t)*16 + h*8 + oi], h=0 hit, h=1 miss.
__global__ void pack_k_kernel(const float* __restrict__ Kh,
                              const float* __restrict__ Km,
                              unsigned* __restrict__ Kpk) {
    int idx = blockIdx.x * 256 + threadIdx.x;
    if (idx >= IC * OG * KTAP * 2 * OPG) return;   // 12800 dwords
    int oi = idx & 7;
    int h  = (idx >> 3) & 1;
    int t  = (idx >> 4) % KTAP;
    int cg = (idx >> 4) / KTAP;
    int g  = cg & (OG - 1), c = cg >> 2;
    int o  = g * OPG + oi;
    const float* K = h ? Km : Kh;
    float k = -K[(o * IC + c) * KTAP + t];
    _Float16 nk = (_Float16)k;
    unsigned short us = __builtin_bit_cast(unsigned short, nk);
    Kpk[idx] = (unsigned)us | ((unsigned)us << 16);
}

// ---------------------------------------------------------------------------
// Tight-loop LDS variant. Block = 256 thr (4 waves), wave w -> output row
// ibase+w. x tile (8 rows) staged in LDS as f16x2 in TWO copies: A = pairs
// (2m,2m+1), B = pairs (2m+1,2m+2) -> any tap v is ONE ds_read_b32.
// u-loop ROLLED so the hot body is ~170 insts (~1.4KB): tests the
// instruction-fetch-bound hypothesis. Double-buffered over c; K via
// wave-uniform s_load (g = blockIdx.z).
__global__ __launch_bounds__(256, 6) void hitmiss_lds_kernel(
    const float* __restrict__ x,
    const unsigned* __restrict__ Kpk,
    float* __restrict__ out)
{
    __shared__ unsigned lds[2 * 2 * XR * DW + 16];   // [buf][copy][row][dw] + pad
    const int tid  = threadIdx.x;
    const int lane = tid & 63;
    const int w    = tid >> 6;            // wave id 0..3
    const int ibase = blockIdx.x * RPB;   // first output row of this block
    const int b = blockIdx.y, g = blockIdx.z;
    const int j0 = lane * 2;

    // staging role: thread -> (x-row sr, dword-quad sq)
    const int sr = tid >> 5;              // 0..7
    const int sq = tid & 31;              // 0..31
    const int scol = sq * 4;

    h2 hit[OPG], miss[OPG];
    const h2 pinf = {(_Float16)INFINITY, (_Float16)INFINITY};
    const h2 ninf = {(_Float16)(-INFINITY), (_Float16)(-INFINITY)};
#pragma unroll
    for (int oi = 0; oi < OPG; ++oi) { hit[oi] = pinf; miss[oi] = ninf; }

    // ---- stage c = 0 into buf 0
    {
        const float* xr = x + (((size_t)(b * IC + 0) * HW_) + ibase + sr) * HW_ + scol;
        const float4 f = *(const float4*)xr;
        const float f4 = (scol + 4 < HW_) ? xr[4] : 0.f;
        const int ba = 0 * 2 * XR * DW + sr * DW + 2 * sq;
        lds[ba]     = pkf(f.x, f.y);
        lds[ba + 1] = pkf(f.z, f.w);
        lds[ba + XR * DW]     = pkf(f.y, f.z);
        lds[ba + XR * DW + 1] = pkf(f.w, f4);
    }

#pragma unroll 1
    for (int c = 0; c < IC; ++c) {
        __syncthreads();                  // stage of buf (c&1) complete
        const int buf = c & 1;

        // early-issue next tile's global loads (latency hides under compute)
        float4 nf = {0.f, 0.f, 0.f, 0.f};
        float nf4 = 0.f;
        if (c + 1 < IC) {
            const float* xr = x + (((size_t)(b * IC + (c + 1)) * HW_) + ibase + sr) * HW_ + scol;
            nf = *(const float4*)xr;
            if (scol + 4 < HW_) nf4 = xr[4];
        }

        const unsigned* kc = Kpk + (size_t)((c * OG + g) * KTAP) * 16;
#pragma unroll 1                          // SMALL hot body: ~170 insts
        for (int u = 0; u < KS; ++u) {
            const unsigned* ku = kc + u * KS * 16;     // 80 dwords, s_load'able
            const int ra = buf * 2 * XR * DW + (w + u) * DW + lane;
            // xv[v]: v0=A+0, v1=B+0, v2=A+1, v3=B+1, v4=A+2 (const indices)
            const h2 xv[KS] = {
                bc2(lds[ra]),
                bc2(lds[ra + XR * DW]),
                bc2(lds[ra + 1]),
                bc2(lds[ra + XR * DW + 1]),
                bc2(lds[ra + 2]) };
#pragma unroll
            for (int v = 0; v < KS; ++v) {
#pragma unroll
                for (int oi = 0; oi < OPG; ++oi) {
                    const h2 nh = bc2(ku[v * 16 + oi]);
                    const h2 nm = bc2(ku[v * 16 + 8 + oi]);
                    hit[oi]  = __builtin_elementwise_min(xv[v] + nh, hit[oi]);
                    miss[oi] = __builtin_elementwise_max(xv[v] + nm, miss[oi]);
                }
            }
        }

        // write next tile into the other buffer (read of it gated by next barrier)
        if (c + 1 < IC) {
            const int ba = (buf ^ 1) * 2 * XR * DW + sr * DW + 2 * sq;
            lds[ba]     = pkf(nf.x, nf.y);
            lds[ba + 1] = pkf(nf.z, nf.w);
            lds[ba + XR * DW]     = pkf(nf.y, nf.z);
            lds[ba + XR * DW + 1] = pkf(nf.w, nf4);
        }
    }

    if (j0 < FH) {
        const int i0 = ibase + w;
#pragma unroll
        for (int oi = 0; oi < OPG; ++oi) {
            const h2 res = hit[oi] - miss[oi];
            const int o = g * OPG + oi;
            float2 st; st.x = (float)res[0]; st.y = (float)res[1];
            *(float2*)(out + (((size_t)b * OC + o) * FH + i0) * FH + j0) = st;
        }
    }
}

// ---------------------------------------------------------------------------
// f32 fallback (K in original (O,C,5,5) layout) — only used if d_ws is too
// small for the packed K table.
__global__ __launch_bounds__(128) void hitmiss_f32_kernel(
    const float* __restrict__ x,
    const float* __restrict__ Kh,
    const float* __restrict__ Km,
    float* __restrict__ out)
{
    const int j = threadIdx.x;
    const int i = blockIdx.x;
    const int b = blockIdx.y;
    if (j >= FH) return;

    float hit[OC], miss[OC];
#pragma unroll
    for (int o = 0; o < OC; ++o) { hit[o] = INFINITY; miss[o] = -INFINITY; }

#pragma unroll 1
    for (int c = 0; c < IC; ++c) {
        const float* xp = x + (((b * IC + c) * HW_) + i) * HW_ + j;
        float xw[KTAP];
#pragma unroll
        for (int u = 0; u < KS; ++u)
#pragma unroll
            for (int v = 0; v < KS; ++v)
                xw[u * KS + v] = xp[u * HW_ + v];
#pragma unroll
        for (int t = 0; t < KTAP - 1; t += 2) {
            const float x0 = xw[t], x1 = xw[t + 1];
#pragma unroll
            for (int o = 0; o < OC; ++o) {
                const float kh0 = Kh[(o * IC + c) * KTAP + t];
                const float kh1 = Kh[(o * IC + c) * KTAP + t + 1];
                const float km0 = Km[(o * IC + c) * KTAP + t];
                const float km1 = Km[(o * IC + c) * KTAP + t + 1];
                hit[o]  = fminf(fminf(x0 - kh0, x1 - kh1), hit[o]);
                miss[o] = fmaxf(fmaxf(x0 - km0, x1 - km1), miss[o]);
            }
        }
        {
            const float x0 = xw[KTAP - 1];
#pragma unroll
            for (int o = 0; o < OC; ++o) {
                hit[o]  = fminf(hit[o],  x0 - Kh[(o * IC + c) * KTAP + KTAP - 1]);
                miss[o] = fmaxf(miss[o], x0 - Km[(o * IC + c) * KTAP + KTAP - 1]);
            }
        }
    }

    float* op = out + ((size_t)(b * OC) * FH + i) * FH + j;
#pragma unroll
    for (int o = 0; o < OC; ++o)
        op[(size_t)o * FH * FH] = hit[o] - miss[o];
}

extern "C" void kernel_launch(void* const* d_in, const int* in_sizes, int n_in,
                              void* d_out, int out_size, void* d_ws, size_t ws_size,
                              hipStream_t stream) {
    const float* x  = (const float*)d_in[0];
    const float* Kh = (const float*)d_in[1];
    const float* Km = (const float*)d_in[2];
    float* out = (float*)d_out;

    const size_t kdwords = (size_t)IC * OG * KTAP * 2 * OPG; // 12800 dwords = 51.2 KB
    if (ws_size >= kdwords * sizeof(unsigned)) {
        unsigned* Kpk = (unsigned*)d_ws;
        pack_k_kernel<<<(int)((kdwords + 255) / 256), 256, 0, stream>>>(Kh, Km, Kpk);
        // 124 rows = 31 blocks x 4 rows: no tail anywhere.
        dim3 grid(FH / RPB, B_, OG);
        hitmiss_lds_kernel<<<grid, 256, 0, stream>>>(x, Kpk, out);
    } else {
        dim3 grid(FH, B_);
        hitmiss_f32_kernel<<<grid, 128, 0, stream>>>(x, Kh, Km, out);
    }
}

// Round 9
// 177.294 us; speedup vs baseline: 1.0042x; 1.0042x over previous
//
#include <hip/hip_runtime.h>
#include <math.h>

// Problem constants (from reference)
constexpr int IC   = 8;    // in channels
constexpr int OC   = 32;   // out channels
constexpr int KS   = 5;    // kernel size
constexpr int B_   = 16;   // batch
constexpr int HW_  = 128;  // H = W
constexpr int FH   = 124;  // output spatial (H - KS + 1)
constexpr int KTAP = KS * KS; // 25
constexpr int OG   = 4;    // output-channel groups (blockIdx.z)
constexpr int OPG  = 8;    // output channels per group
constexpr int DW   = HW_ / 2;                    // 64 packed dwords per row
constexpr size_t NXD = (size_t)B_ * IC * HW_ * DW; // 1,048,576 dwords per copy

typedef _Float16 h2 __attribute__((ext_vector_type(2)));

__device__ __forceinline__ h2 bc2(unsigned u) { return __builtin_bit_cast(h2, u); }
__device__ __forceinline__ unsigned pkf(float a, float b) {
    return __builtin_bit_cast(unsigned, __builtin_amdgcn_cvt_pkrtz(a, b));
}

// ---------------------------------------------------------------------------
// Pack -K_hit / -K_miss into f16x2 broadcast pairs.
// Layout: Kpk[((c*OG+g)*KTAP + t)*16 + h*8 + oi], h=0 hit, h=1 miss.
__global__ void pack_k_kernel(const float* __restrict__ Kh,
                              const float* __restrict__ Km,
                              unsigned* __restrict__ Kpk) {
    int idx = blockIdx.x * 256 + threadIdx.x;
    if (idx >= IC * OG * KTAP * 2 * OPG) return;   // 12800 dwords
    int oi = idx & 7;
    int h  = (idx >> 3) & 1;
    int t  = (idx >> 4) % KTAP;
    int cg = (idx >> 4) / KTAP;
    int g  = cg & (OG - 1), c = cg >> 2;
    int o  = g * OPG + oi;
    const float* K = h ? Km : Kh;
    float k = -K[(o * IC + c) * KTAP + t];
    _Float16 nk = (_Float16)k;
    unsigned short us = __builtin_bit_cast(unsigned short, nk);
    Kpk[idx] = (unsigned)us | ((unsigned)us << 16);
}

// ---------------------------------------------------------------------------
// Pre-pack x into TWO f16x2 copies:
//   A[m] = (x[2m],   x[2m+1])   (even-aligned pairs)
//   B[m] = (x[2m+1], x[2m+2])   (odd-aligned pairs; last pads 0)
// so any tap v of a pixel-pair is ONE dword: v even -> A[lane + v/2],
// v odd -> B[lane + v/2]. Removes ALL cvt/repack VALU from the hot kernel.
__global__ void pack_x_kernel(const float* __restrict__ x,
                              unsigned* __restrict__ wsA) {
    unsigned* wsB = wsA + NXD;
    size_t idx = (size_t)blockIdx.x * 256 + threadIdx.x;
    if (idx >= NXD) return;
    int m = (int)(idx & (DW - 1));
    size_t row = idx >> 6;
    const float* xr = x + row * HW_ + 2 * m;
    float a0 = xr[0], a1 = xr[1];
    float a2 = (m < DW - 1) ? xr[2] : 0.f;
    wsA[idx] = pkf(a0, a1);
    wsB[idx] = pkf(a1, a2);
}

// ---------------------------------------------------------------------------
// Pure-pk hot kernel. Block = 128 thr (2 waves); wave w -> output row
// blockIdx.x*2 + w. Lane = pixel pair (j0, j0+1); 8 channels (g=blockIdx.z,
// K wave-uniform via s_load). Per (c,u): 5 dword loads (VMEM pipe) + 160
// v_pk insts -> VALU stream is >98% pk ops. No LDS, no barriers, no cvt.
__global__ __launch_bounds__(128, 8) void hitmiss_pk_kernel(
    const unsigned* __restrict__ xpk,
    const unsigned* __restrict__ Kpk,
    float* __restrict__ out)
{
    const int lane = threadIdx.x & 63;
    const int w    = threadIdx.x >> 6;
    const int i = blockIdx.x * 2 + w;
    const int b = blockIdx.y, g = blockIdx.z;
    const int j0 = lane * 2;

    h2 hit[OPG], miss[OPG];
    const h2 pinf = {(_Float16)INFINITY, (_Float16)INFINITY};
    const h2 ninf = {(_Float16)(-INFINITY), (_Float16)(-INFINITY)};
#pragma unroll
    for (int oi = 0; oi < OPG; ++oi) { hit[oi] = pinf; miss[oi] = ninf; }

    const unsigned* rbase = xpk + ((size_t)(b * IC) * HW_ + i) * DW + lane;

#pragma unroll 1   // c rolled; per-c body ~6.7KB (25 loads + 800 pk)
    for (int c = 0; c < IC; ++c) {
        const unsigned* kc = Kpk + (size_t)((c * OG + g) * KTAP) * 16;
        const unsigned* rc = rbase + (size_t)c * HW_ * DW;
#pragma unroll
        for (int u = 0; u < KS; ++u) {
            const unsigned* ra = rc + u * DW;
            // xv[v]: v even -> copyA[lane+v/2], v odd -> copyB[lane+v/2]
            const h2 xv[KS] = { bc2(ra[0]),       bc2(ra[NXD]),
                                bc2(ra[1]),       bc2(ra[NXD + 1]),
                                bc2(ra[2]) };
            const unsigned* ku = kc + u * KS * 16;
#pragma unroll
            for (int v = 0; v < KS; ++v) {
#pragma unroll
                for (int oi = 0; oi < OPG; ++oi) {
                    const h2 nh = bc2(ku[v * 16 + oi]);
                    const h2 nm = bc2(ku[v * 16 + 8 + oi]);
                    hit[oi]  = __builtin_elementwise_min(xv[v] + nh, hit[oi]);
                    miss[oi] = __builtin_elementwise_max(xv[v] + nm, miss[oi]);
                }
            }
        }
    }

    if (j0 < FH) {
#pragma unroll
        for (int oi = 0; oi < OPG; ++oi) {
            const h2 res = hit[oi] - miss[oi];
            const int o = g * OPG + oi;
            float2 st; st.x = (float)res[0]; st.y = (float)res[1];
            *(float2*)(out + (((size_t)b * OC + o) * FH + i) * FH + j0) = st;
        }
    }
}

// ---------------------------------------------------------------------------
// Mid fallback (R4's best 112us kernel): f16 pk with inline cvt, K packed only.
__global__ __launch_bounds__(64, 6) void hitmiss_f16_kernel(
    const float* __restrict__ x,
    const unsigned* __restrict__ Kpk,
    float* __restrict__ out)
{
    const int lane = threadIdx.x;
    const int i = blockIdx.x, b = blockIdx.y, g = blockIdx.z;
    const int j0 = lane * 2;
    if (j0 >= FH) return;

    h2 hit[OPG], miss[OPG];
    const h2 pinf = {(_Float16)INFINITY, (_Float16)INFINITY};
    const h2 ninf = {(_Float16)(-INFINITY), (_Float16)(-INFINITY)};
#pragma unroll
    for (int oi = 0; oi < OPG; ++oi) { hit[oi] = pinf; miss[oi] = ninf; }

#pragma unroll 1
    for (int c = 0; c < IC; ++c) {
        const float* xp = x + (((b * IC + c) * HW_) + i) * HW_ + j0;
        h2 xpk[KTAP];
#pragma unroll
        for (int u = 0; u < KS; ++u) {
            const float2 f0 = *(const float2*)(xp + u * HW_);
            const float2 f1 = *(const float2*)(xp + u * HW_ + 2);
            const float2 f2 = *(const float2*)(xp + u * HW_ + 4);
            const float fv[6] = {f0.x, f0.y, f1.x, f1.y, f2.x, f2.y};
#pragma unroll
            for (int v = 0; v < KS; ++v)
                xpk[u * KS + v] = __builtin_bit_cast(h2,
                    __builtin_amdgcn_cvt_pkrtz(fv[v], fv[v + 1]));
        }
        const unsigned* kc = Kpk + (size_t)((c * OG + g) * KTAP) * 16;
#pragma unroll
        for (int t = 0; t < KTAP; ++t) {
#pragma unroll
            for (int oi = 0; oi < OPG; ++oi) {
                const h2 nh = bc2(kc[t * 16 + oi]);
                const h2 nm = bc2(kc[t * 16 + 8 + oi]);
                hit[oi]  = __builtin_elementwise_min(xpk[t] + nh, hit[oi]);
                miss[oi] = __builtin_elementwise_max(xpk[t] + nm, miss[oi]);
            }
        }
    }

#pragma unroll
    for (int oi = 0; oi < OPG; ++oi) {
        const h2 res = hit[oi] - miss[oi];
        const int o = g * OPG + oi;
        float* op = out + (((size_t)b * OC + o) * FH + i) * FH + j0;
        op[0] = (float)res[0];
        op[1] = (float)res[1];
    }
}

// ---------------------------------------------------------------------------
// f32 last-resort fallback (K in original layout).
__global__ __launch_bounds__(128) void hitmiss_f32_kernel(
    const float* __restrict__ x,
    const float* __restrict__ Kh,
    const float* __restrict__ Km,
    float* __restrict__ out)
{
    const int j = threadIdx.x;
    const int i = blockIdx.x;
    const int b = blockIdx.y;
    if (j >= FH) return;

    float hit[OC], miss[OC];
#pragma unroll
    for (int o = 0; o < OC; ++o) { hit[o] = INFINITY; miss[o] = -INFINITY; }

#pragma unroll 1
    for (int c = 0; c < IC; ++c) {
        const float* xp = x + (((b * IC + c) * HW_) + i) * HW_ + j;
        float xw[KTAP];
#pragma unroll
        for (int u = 0; u < KS; ++u)
#pragma unroll
            for (int v = 0; v < KS; ++v)
                xw[u * KS + v] = xp[u * HW_ + v];
#pragma unroll
        for (int t = 0; t < KTAP; ++t) {
            const float x0 = xw[t];
#pragma unroll
            for (int o = 0; o < OC; ++o) {
                hit[o]  = fminf(hit[o],  x0 - Kh[(o * IC + c) * KTAP + t]);
                miss[o] = fmaxf(miss[o], x0 - Km[(o * IC + c) * KTAP + t]);
            }
        }
    }

    float* op = out + ((size_t)(b * OC) * FH + i) * FH + j;
#pragma unroll
    for (int o = 0; o < OC; ++o)
        op[(size_t)o * FH * FH] = hit[o] - miss[o];
}

extern "C" void kernel_launch(void* const* d_in, const int* in_sizes, int n_in,
                              void* d_out, int out_size, void* d_ws, size_t ws_size,
                              hipStream_t stream) {
    const float* x  = (const float*)d_in[0];
    const float* Kh = (const float*)d_in[1];
    const float* Km = (const float*)d_in[2];
    float* out = (float*)d_out;

    const size_t kdwords = (size_t)IC * OG * KTAP * 2 * OPG;  // 12800
    const size_t need_full = (2 * NXD + kdwords) * sizeof(unsigned); // ~8.44 MB

    if (ws_size >= need_full) {
        // Layout: [copyA | copyB | Kpk]  (Kpk last so edge-lane overreads of
        // copyB land in Kpk, staying inside the allocation).
        unsigned* wsA = (unsigned*)d_ws;
        unsigned* Kpk = wsA + 2 * NXD;
        pack_k_kernel<<<(int)((kdwords + 255) / 256), 256, 0, stream>>>(Kh, Km, Kpk);
        pack_x_kernel<<<(int)(NXD / 256), 256, 0, stream>>>(x, wsA);
        dim3 grid(FH / 2, B_, OG);   // 62 x 16 x 4, no tails (124 = 62*2)
        hitmiss_pk_kernel<<<grid, 128, 0, stream>>>(wsA, Kpk, out);
    } else if (ws_size >= kdwords * sizeof(unsigned)) {
        unsigned* Kpk = (unsigned*)d_ws;
        pack_k_kernel<<<(int)((kdwords + 255) / 256), 256, 0, stream>>>(Kh, Km, Kpk);
        dim3 grid(FH, B_, OG);
        hitmiss_f16_kernel<<<grid, 64, 0, stream>>>(x, Kpk, out);
    } else {
        dim3 grid(FH, B_);
        hitmiss_f32_kernel<<<grid, 128, 0, stream>>>(x, Kh, Km, out);
    }
}